// Round 8
// baseline (12687.787 us; speedup 1.0000x reference)
//
#include <hip/hip_runtime.h>
#include <math.h>

#define SCALE_F 0.03125f   // 1/sqrt(1024)

// =====================================================================
// fp32 tiled GEMM: C[M,N] = A[M,K] @ (BT ? B[N,K]^T : B[K,N])
// EPI: 0 = none, 1 = silu
// =====================================================================
template<bool BT, int EPI>
__global__ __launch_bounds__(256) void gemm_nt(const float* __restrict__ A,
                                               const float* __restrict__ Bm,
                                               float* __restrict__ C,
                                               int M, int N, int K) {
  __shared__ float As[32][68];
  __shared__ float Bs[32][68];
  const int tid = threadIdx.x;
  const int n0 = blockIdx.x * 64;
  const int m0 = blockIdx.y * 64;
  const int i0 = (tid >> 4) * 4;
  const int j0 = (tid & 15) * 4;
  float acc[4][4] = {};

  for (int k0 = 0; k0 < K; k0 += 32) {
#pragma unroll
    for (int s = 0; s < 2; ++s) {
      int id = tid + 256 * s;
      int r = id >> 3, c4 = id & 7;
      float4 v = *(const float4*)&A[(size_t)(m0 + r) * K + k0 + c4 * 4];
      As[c4 * 4 + 0][r] = v.x; As[c4 * 4 + 1][r] = v.y;
      As[c4 * 4 + 2][r] = v.z; As[c4 * 4 + 3][r] = v.w;
    }
    if (BT) {
#pragma unroll
      for (int s = 0; s < 2; ++s) {
        int id = tid + 256 * s;
        int r = id >> 3, c4 = id & 7;
        float4 v = *(const float4*)&Bm[(size_t)(n0 + r) * K + k0 + c4 * 4];
        Bs[c4 * 4 + 0][r] = v.x; Bs[c4 * 4 + 1][r] = v.y;
        Bs[c4 * 4 + 2][r] = v.z; Bs[c4 * 4 + 3][r] = v.w;
      }
    } else {
#pragma unroll
      for (int s = 0; s < 2; ++s) {
        int id = tid + 256 * s;
        int kk = id >> 4, c4 = id & 15;
        float4 v = *(const float4*)&Bm[(size_t)(k0 + kk) * N + n0 + c4 * 4];
        *(float4*)&Bs[kk][c4 * 4] = v;
      }
    }
    __syncthreads();
#pragma unroll
    for (int kk = 0; kk < 32; ++kk) {
      float4 a = *(const float4*)&As[kk][i0];
      float4 b = *(const float4*)&Bs[kk][j0];
      float av[4] = {a.x, a.y, a.z, a.w};
      float bv[4] = {b.x, b.y, b.z, b.w};
#pragma unroll
      for (int ii = 0; ii < 4; ++ii)
#pragma unroll
        for (int jj = 0; jj < 4; ++jj)
          acc[ii][jj] = fmaf(av[ii], bv[jj], acc[ii][jj]);
    }
    __syncthreads();
  }

#pragma unroll
  for (int ii = 0; ii < 4; ++ii) {
    float4 v;
    float* vp = (float*)&v;
#pragma unroll
    for (int jj = 0; jj < 4; ++jj) {
      float x = acc[ii][jj];
      if (EPI == 1) x = x / (1.0f + __expf(-x));
      vp[jj] = x;
    }
    *(float4*)&C[(size_t)(m0 + i0 + ii) * N + n0 + j0] = v;
  }
}

// =====================================================================
// Mailbox primitives: 8-byte (float value | 32-bit step tag), agent scope.
// =====================================================================
typedef unsigned long long u64;
__device__ __forceinline__ u64 ald64(const u64* p) {
  return __hip_atomic_load(p, __ATOMIC_RELAXED, __HIP_MEMORY_SCOPE_AGENT);
}
__device__ __forceinline__ void ast64(u64* p, u64 v) {
  __hip_atomic_store(p, v, __ATOMIC_RELAXED, __HIP_MEMORY_SCOPE_AGENT);
}
__device__ __forceinline__ u64 pk(float v, int j) {
  return ((u64)(unsigned)j << 32) | (u64)__float_as_uint(v);
}
__device__ __forceinline__ float lo(u64 u) {
  return __uint_as_float((unsigned)u);
}
__device__ __forceinline__ float pollv(const u64* p, int j) {
  u64 u = ald64(p);
  while ((unsigned)(u >> 32) != (unsigned)j) {
    __builtin_amdgcn_s_sleep(1);
    u = ald64(p);
  }
  return lo(u);
}

// Rotated tape addressing.
#define TIDX(n, e) ((n) * 64 + (((e) + (n)) & 63))

// 64 named weight scalars/thread (one row of W_h AND W_wr, 32 strided cols).
// HARD LESSONS: (1) local arrays -> scratch; (2) VGPR budget = 65536/block,
// immovable; 64 floats + working set fits 128 (R5/R7: VGPR=104/128).
#define REP32(M) M(0) M(1) M(2) M(3) M(4) M(5) M(6) M(7) M(8) M(9) M(10) \
  M(11) M(12) M(13) M(14) M(15) M(16) M(17) M(18) M(19) M(20) M(21) M(22) \
  M(23) M(24) M(25) M(26) M(27) M(28) M(29) M(30) M(31)

#define RW(i) const float wh##i = Whp[32 * (i)]; \
              const float ww##i = Wwp[32 * (i)];
#define MVI(i) { float4 hh = ht4[cseg + 32 * (i)]; \
  ah0 = fmaf(wh##i, hh.x, ah0); ah1 = fmaf(wh##i, hh.y, ah1); \
  ah2 = fmaf(wh##i, hh.z, ah2); ah3 = fmaf(wh##i, hh.w, ah3); \
  aw0 = fmaf(ww##i, hh.x, aw0); aw1 = fmaf(ww##i, hh.y, aw1); \
  aw2 = fmaf(ww##i, hh.z, aw2); aw3 = fmaf(ww##i, hh.w, aw3); }

#define TAGOK(u) ((unsigned)((u) >> 32) == tj)

// =====================================================================
// Group-shared persistent scan: 256 wgs x 512 threads (1 wg/CU, 8 waves).
// 4 groups of 64 wgs; group g serves batches 4g..4g+3. wg (b_loc, es):
// owner of (bsel, es-slice) AND producer of rows R0=[es*64+b_loc*16,+16)
// of BOTH mats for all 4 batches. All cross-wg values are (value|tag)
// mailboxes. Round-8 changes vs R7:
//  - S0 polls are BATCHED (10 independent loads per retry -> ~1 latency
//    instead of 10 serial spin loops) and h_t written as float4 (no
//    stride-4 8-way write conflicts).
//  - qp partials published per-WAVE directly from S1 (shfl 32 combine,
//    qp2b[B][512]) -> the qp hop merges into the Rh/wv hop; qtmp gone.
// =====================================================================
__global__ __launch_bounds__(512) void scan_kernel(
    const float* __restrict__ W_h, const float* __restrict__ W_wr,
    const float* __restrict__ b_h, const float* __restrict__ gate,
    float* __restrict__ wx,       // [B][T][D]; rows overwritten with h*gate
    u64* __restrict__ h2,         // [B][1024] h mailboxes
    u64* __restrict__ ps2,        // [B][16][64] score-partial mailboxes
    u64* __restrict__ Rh2,        // [B][1024]
    u64* __restrict__ wv2,        // [B][1024]
    u64* __restrict__ qp2b,       // [B][512] per-wave q partials
    float* __restrict__ hfin,     // [B][1024] final h_work (plain)
    float* __restrict__ tape_out) // [B][64][1024]
{
  const int tid  = threadIdx.x;
  const int wg   = blockIdx.x;
  const int g    = wg >> 6;
  const int idx  = wg & 63;
  const int b_loc = idx >> 4;
  const int es   = idx & 15;
  const int gb   = g * 4;
  const int bsel = gb + b_loc;
  const int E0   = es * 64;
  const int R0   = es * 64 + b_loc * 16;
  const int w    = tid >> 6;
  const int lane = tid & 63;
  const int row  = tid >> 5;      // 0..15
  const int cseg = tid & 31;      // 32 col segments
  const int gr   = R0 + row;      // produced row (both mats)
  const int nwr  = tid >> 3;      // tape slot n
  const int ksb  = tid & 7;       // 8-elem e-block

  __shared__ float h_t[4096];       // batch-transposed h: h_t[4d+b], 16 KB
  __shared__ float tape_l[4096];    // rotated, 16 KB
  __shared__ float ws_lds[64], wa_lds[64], attn_lds[64];
  __shared__ float wv_lds[64], Rh_lds[64], h_own[64], read_lds[64];
  // Pad past 80 KB: exactly 1 wg/CU.
  __shared__ volatile float lds_pad[12288];
  lds_pad[tid] = 0.0f; lds_pad[tid + 512] = 0.0f;

  // ---- weight preload: row gr of W_h AND W_wr, cols cseg+32i ----
  const float* Whp = W_h + (size_t)gr * 1024 + cseg;
  const float* Wwp = W_wr + (size_t)gr * 1024 + cseg;
  REP32(RW)

  const float4* ht4 = (const float4*)h_t;

  for (int i = tid; i < 4096; i += 512) tape_l[i] = 0.0f;

  float bh_r = 0.0f;
  if (w == 0) bh_r = b_h[E0 + lane];
  __syncthreads();

  // ---- prologue: h(1) = tanh(wx0 + b_h) tag 1; ps tag 1 (= 0) ----
  if (w == 0) {
    size_t xi = (size_t)bsel * 1048576 + E0 + lane;
    float hv = tanhf(wx[xi] + bh_r);
    h_own[lane] = hv;
    ast64(&h2[(size_t)bsel * 1024 + E0 + lane], pk(hv, 1));
    wx[xi] = hv * gate[xi];                 // output row 0
  }
  if (tid < 64) ast64(&ps2[(size_t)bsel * 1024 + es * 64 + tid], pk(0.0f, 1));
  __syncthreads();

  for (int j = 1; j <= 1024; ++j) {
    const bool last = (j == 1024);
    const unsigned tj = (unsigned)j;

    // ---- S0: BATCHED staging: 8 h + 2 ps polls in one retry loop ----
    float p0, p1;
    {
      const int d0 = tid, d1 = tid + 512;
      const u64* hp = &h2[(size_t)gb * 1024];
      const u64* pA = &ps2[(size_t)bsel * 1024 + (ksb * 2) * 64 + nwr];
      const u64* pB = &ps2[(size_t)bsel * 1024 + (ksb * 2 + 1) * 64 + nwr];
      u64 a0, a1, a2, a3, c0, c1, c2, c3, u0, u1;
      for (;;) {
        a0 = ald64(hp + 0 * 1024 + d0); a1 = ald64(hp + 1 * 1024 + d0);
        a2 = ald64(hp + 2 * 1024 + d0); a3 = ald64(hp + 3 * 1024 + d0);
        c0 = ald64(hp + 0 * 1024 + d1); c1 = ald64(hp + 1 * 1024 + d1);
        c2 = ald64(hp + 2 * 1024 + d1); c3 = ald64(hp + 3 * 1024 + d1);
        u0 = ald64(pA); u1 = ald64(pB);
        if (TAGOK(a0) && TAGOK(a1) && TAGOK(a2) && TAGOK(a3) &&
            TAGOK(c0) && TAGOK(c1) && TAGOK(c2) && TAGOK(c3) &&
            TAGOK(u0) && TAGOK(u1)) break;
        __builtin_amdgcn_s_sleep(1);
      }
      ((float4*)h_t)[d0] = make_float4(lo(a0), lo(a1), lo(a2), lo(a3));
      ((float4*)h_t)[d1] = make_float4(lo(c0), lo(c1), lo(c2), lo(c3));
      p0 = lo(u0); p1 = lo(u1);
    }
    float wxv = 0.0f, gv = 0.0f;
    size_t xj = 0;
    if (w == 0 && !last) {
      xj  = (size_t)bsel * 1048576 + (size_t)j * 1024 + E0 + lane;
      wxv = wx[xj];
      gv  = gate[xj];
    }
    __syncthreads();   // B1

    // ---- S1: ws reduce; matvec; publish Rh/wv + per-wave qp ----
    {
      float s = p0 + p1;
      s += __shfl_xor(s, 1);
      s += __shfl_xor(s, 2);
      s += __shfl_xor(s, 4);
      if (ksb == 0) ws_lds[nwr] = s;
    }
    float ah0 = 0.0f, ah1 = 0.0f, ah2 = 0.0f, ah3 = 0.0f;
    float aw0 = 0.0f, aw1 = 0.0f, aw2 = 0.0f, aw3 = 0.0f;
    REP32(MVI)
#pragma unroll
    for (int m = 1; m < 32; m <<= 1) {
      ah0 += __shfl_xor(ah0, m); ah1 += __shfl_xor(ah1, m);
      ah2 += __shfl_xor(ah2, m); ah3 += __shfl_xor(ah3, m);
      aw0 += __shfl_xor(aw0, m); aw1 += __shfl_xor(aw1, m);
      aw2 += __shfl_xor(aw2, m); aw3 += __shfl_xor(aw3, m);
    }
    // per-wave qp partial: rows 2w,2w+1 combined via shfl 32
    {
      float4 hrow = ht4[gr];
      float t0 = aw0 * hrow.x, t1 = aw1 * hrow.y;
      float t2 = aw2 * hrow.z, t3 = aw3 * hrow.w;
      t0 += __shfl_xor(t0, 32); t1 += __shfl_xor(t1, 32);
      t2 += __shfl_xor(t2, 32); t3 += __shfl_xor(t3, 32);
      if (lane == 0) {
        ast64(&qp2b[(size_t)(gb + 0) * 512 + idx * 8 + w], pk(t0, j));
        ast64(&qp2b[(size_t)(gb + 1) * 512 + idx * 8 + w], pk(t1, j));
        ast64(&qp2b[(size_t)(gb + 2) * 512 + idx * 8 + w], pk(t2, j));
        ast64(&qp2b[(size_t)(gb + 3) * 512 + idx * 8 + w], pk(t3, j));
      }
    }
    if (cseg == 0) {
      ast64(&Rh2[(size_t)(gb + 0) * 1024 + gr], pk(ah0, j));
      ast64(&Rh2[(size_t)(gb + 1) * 1024 + gr], pk(ah1, j));
      ast64(&Rh2[(size_t)(gb + 2) * 1024 + gr], pk(ah2, j));
      ast64(&Rh2[(size_t)(gb + 3) * 1024 + gr], pk(ah3, j));
      ast64(&wv2[(size_t)(gb + 0) * 1024 + gr], pk(aw0, j));
      ast64(&wv2[(size_t)(gb + 1) * 1024 + gr], pk(aw1, j));
      ast64(&wv2[(size_t)(gb + 2) * 1024 + gr], pk(aw2, j));
      ast64(&wv2[(size_t)(gb + 3) * 1024 + gr], pk(aw3, j));
    }
    __syncthreads();   // B2

    // ---- S2: wave-parallel: wa | q+attn | wv gather | Rh gather ----
    if (w == 0) {
      float s = ws_lds[lane] * SCALE_F;
      float m = s;
#pragma unroll
      for (int off = 1; off < 64; off <<= 1) m = fmaxf(m, __shfl_xor(m, off));
      float ex = __expf(s - m);
      float sum = ex;
#pragma unroll
      for (int off = 1; off < 64; off <<= 1) sum += __shfl_xor(sum, off);
      wa_lds[lane] = ex / sum;
    } else if (w == 1) {
      if (!last) {
        // batched poll of 8 q partials
        const u64* qb = &qp2b[(size_t)bsel * 512 + lane * 8];
        u64 q0, q1, q2, q3, q4, q5, q6, q7;
        for (;;) {
          q0 = ald64(qb + 0); q1 = ald64(qb + 1); q2 = ald64(qb + 2);
          q3 = ald64(qb + 3); q4 = ald64(qb + 4); q5 = ald64(qb + 5);
          q6 = ald64(qb + 6); q7 = ald64(qb + 7);
          if (TAGOK(q0) && TAGOK(q1) && TAGOK(q2) && TAGOK(q3) &&
              TAGOK(q4) && TAGOK(q5) && TAGOK(q6) && TAGOK(q7)) break;
          __builtin_amdgcn_s_sleep(1);
        }
        float qv = lo(q0) + lo(q1) + lo(q2) + lo(q3) +
                   lo(q4) + lo(q5) + lo(q6) + lo(q7);
#pragma unroll
        for (int off = 1; off < 64; off <<= 1) qv += __shfl_xor(qv, off);
        // redundant own wa, rs identity, attn
        float wsr = ws_lds[lane];
        float sm = wsr * SCALE_F;
        float m = sm;
#pragma unroll
        for (int off = 1; off < 64; off <<= 1) m = fmaxf(m, __shfl_xor(m, off));
        float ex = __expf(sm - m);
        float sum = ex;
#pragma unroll
        for (int off = 1; off < 64; off <<= 1) sum += __shfl_xor(sum, off);
        float wa_l = ex / sum;
        float rs = fmaf(wa_l, qv - wsr, wsr) * SCALE_F;
        float m2 = rs;
#pragma unroll
        for (int off = 1; off < 64; off <<= 1) m2 = fmaxf(m2, __shfl_xor(m2, off));
        float ex2 = __expf(rs - m2);
        float sum2 = ex2;
#pragma unroll
        for (int off = 1; off < 64; off <<= 1) sum2 += __shfl_xor(sum2, off);
        attn_lds[lane] = ex2 / sum2;
      }
    } else if (w == 2) {
      wv_lds[lane] = pollv(&wv2[(size_t)bsel * 1024 + E0 + lane], j);
    } else if (w == 3) {
      Rh_lds[lane] = pollv(&Rh2[(size_t)bsel * 1024 + E0 + lane], j);
    }
    __syncthreads();   // B3

    // ---- S3: tape lerp ----
    {
      float wa = wa_lds[nwr];
#pragma unroll
      for (int i = 0; i < 8; ++i) {
        int e = ksb * 8 + i;
        int ix = TIDX(nwr, e);
        float t = tape_l[ix];
        tape_l[ix] = fmaf(wa, wv_lds[e] - t, t);
      }
    }
    if (last) break;
    __syncthreads();   // B4

    // ---- S4: read gather: read[e] = sum_n attn[n]*tape[n][e] ----
    {
      int ge = tid >> 3, gn = tid & 7;
      float gsum = 0.0f;
#pragma unroll
      for (int i = 0; i < 8; ++i) {
        int n = gn * 8 + i;
        gsum = fmaf(attn_lds[n], tape_l[TIDX(n, ge)], gsum);
      }
      gsum += __shfl_xor(gsum, 1);
      gsum += __shfl_xor(gsum, 2);
      gsum += __shfl_xor(gsum, 4);
      if (gn == 0) read_lds[ge] = gsum;
    }
    __syncthreads();   // B5

    // ---- S5: h(j+1) = tanh(Rh + wx_j + read + b_h); publish tag j+1 ----
    if (w == 0) {
      float hv = tanhf(Rh_lds[lane] + wxv + read_lds[lane] + bh_r);
      h_own[lane] = hv;
      ast64(&h2[(size_t)bsel * 1024 + E0 + lane], pk(hv, j + 1));
      wx[xj] = hv * gv;
    }
    __syncthreads();   // B6

    // ---- S6: ps partials vs updated tape -> publish tag j+1 ----
    {
      float s = 0.0f;
#pragma unroll
      for (int i = 0; i < 8; ++i) {
        int e = ksb * 8 + i;
        s = fmaf(h_own[e], tape_l[TIDX(nwr, e)], s);
      }
      s += __shfl_xor(s, 1);
      s += __shfl_xor(s, 2);
      s += __shfl_xor(s, 4);
      if (ksb == 0) ast64(&ps2[(size_t)bsel * 1024 + es * 64 + nwr], pk(s, j + 1));
    }
    // no barrier: next S0 writes h_t only; B1 orders h_t vs S1 readers.
  }

  // ---- epilogue: final tape slice + final h_work ----
#pragma unroll
  for (int i = 0; i < 8; ++i) {
    int e = ksb * 8 + i;
    tape_out[(size_t)(bsel * 64 + nwr) * 1024 + E0 + e] = tape_l[TIDX(nwr, e)];
  }
  if (w == 0) hfin[(size_t)bsel * 1024 + E0 + lane] = h_own[lane];
}

// =====================================================================
extern "C" void kernel_launch(void* const* d_in, const int* in_sizes, int n_in,
                              void* d_out, int out_size, void* d_ws, size_t ws_size,
                              hipStream_t stream) {
  (void)in_sizes; (void)n_in; (void)out_size; (void)ws_size;
  const float* x      = (const float*)d_in[0];
  const float* in_w   = (const float*)d_in[1];
  const float* out_w  = (const float*)d_in[2];
  const float* gate_w = (const float*)d_in[3];
  const float* W_x    = (const float*)d_in[4];
  const float* W_h    = (const float*)d_in[5];
  const float* W_wr   = (const float*)d_in[6];
  const float* b_h    = (const float*)d_in[7];

  float* out  = (float*)d_out;                     // [16][1024][1024]
  float* tape = out + (size_t)16 * 1024 * 1024;    // [16][64][1024]
  float* hfin = tape + (size_t)16 * 64 * 1024;     // [16][1024]

  float* ws = (float*)d_ws;
  // scan-time mailboxes overlay M1's region (M1 dead before scan)
  u64* h2   = (u64*)ws;                  // 16K pairs
  u64* ps2  = (u64*)(ws + 32768);        // 16K pairs
  u64* Rh2  = (u64*)(ws + 65536);        // 16K pairs
  u64* wv2  = (u64*)(ws + 98304);        // 16K pairs
  u64* qp2b = (u64*)(ws + 131072);       // 8K pairs -> ends at 147456
  float* M1 = ws;                        // [1024][1024]
  float* wx = ws + (1 << 20);            // [16][1024][1024]

  float* gate = out;                     // park gate in d_out region

  dim3 blk(256);
  gemm_nt<false, 0><<<dim3(16, 16), blk, 0, stream>>>(W_x, in_w, M1, 1024, 1024, 1024);
  gemm_nt<true, 1><<<dim3(16, 256), blk, 0, stream>>>(x, gate_w, gate, 16384, 1024, 1024);
  gemm_nt<true, 0><<<dim3(16, 256), blk, 0, stream>>>(x, M1, wx, 16384, 1024, 1024);
  hipMemsetAsync(ws, 0, 147456 * sizeof(float), stream);   // zero tags
  scan_kernel<<<256, 512, 0, stream>>>(W_h, W_wr, b_h, gate, wx, h2, ps2,
                                       Rh2, wv2, qp2b, hfin, tape);
  gemm_nt<true, 0><<<dim3(16, 256), blk, 0, stream>>>(wx, out_w, out, 16384, 1024, 1024);
}

// Round 9
// 11161.868 us; speedup vs baseline: 1.1367x; 1.1367x over previous
//
#include <hip/hip_runtime.h>
#include <math.h>

#define SCALE_F 0.03125f   // 1/sqrt(1024)

// =====================================================================
// fp32 tiled GEMM: C[M,N] = A[M,K] @ (BT ? B[N,K]^T : B[K,N])
// EPI: 0 = none, 1 = silu
// =====================================================================
template<bool BT, int EPI>
__global__ __launch_bounds__(256) void gemm_nt(const float* __restrict__ A,
                                               const float* __restrict__ Bm,
                                               float* __restrict__ C,
                                               int M, int N, int K) {
  __shared__ float As[32][68];
  __shared__ float Bs[32][68];
  const int tid = threadIdx.x;
  const int n0 = blockIdx.x * 64;
  const int m0 = blockIdx.y * 64;
  const int i0 = (tid >> 4) * 4;
  const int j0 = (tid & 15) * 4;
  float acc[4][4] = {};

  for (int k0 = 0; k0 < K; k0 += 32) {
#pragma unroll
    for (int s = 0; s < 2; ++s) {
      int id = tid + 256 * s;
      int r = id >> 3, c4 = id & 7;
      float4 v = *(const float4*)&A[(size_t)(m0 + r) * K + k0 + c4 * 4];
      As[c4 * 4 + 0][r] = v.x; As[c4 * 4 + 1][r] = v.y;
      As[c4 * 4 + 2][r] = v.z; As[c4 * 4 + 3][r] = v.w;
    }
    if (BT) {
#pragma unroll
      for (int s = 0; s < 2; ++s) {
        int id = tid + 256 * s;
        int r = id >> 3, c4 = id & 7;
        float4 v = *(const float4*)&Bm[(size_t)(n0 + r) * K + k0 + c4 * 4];
        Bs[c4 * 4 + 0][r] = v.x; Bs[c4 * 4 + 1][r] = v.y;
        Bs[c4 * 4 + 2][r] = v.z; Bs[c4 * 4 + 3][r] = v.w;
      }
    } else {
#pragma unroll
      for (int s = 0; s < 2; ++s) {
        int id = tid + 256 * s;
        int kk = id >> 4, c4 = id & 15;
        float4 v = *(const float4*)&Bm[(size_t)(k0 + kk) * N + n0 + c4 * 4];
        *(float4*)&Bs[kk][c4 * 4] = v;
      }
    }
    __syncthreads();
#pragma unroll
    for (int kk = 0; kk < 32; ++kk) {
      float4 a = *(const float4*)&As[kk][i0];
      float4 b = *(const float4*)&Bs[kk][j0];
      float av[4] = {a.x, a.y, a.z, a.w};
      float bv[4] = {b.x, b.y, b.z, b.w};
#pragma unroll
      for (int ii = 0; ii < 4; ++ii)
#pragma unroll
        for (int jj = 0; jj < 4; ++jj)
          acc[ii][jj] = fmaf(av[ii], bv[jj], acc[ii][jj]);
    }
    __syncthreads();
  }

#pragma unroll
  for (int ii = 0; ii < 4; ++ii) {
    float4 v;
    float* vp = (float*)&v;
#pragma unroll
    for (int jj = 0; jj < 4; ++jj) {
      float x = acc[ii][jj];
      if (EPI == 1) x = x / (1.0f + __expf(-x));
      vp[jj] = x;
    }
    *(float4*)&C[(size_t)(m0 + i0 + ii) * N + n0 + j0] = v;
  }
}

// =====================================================================
// Agent-scope helpers. Plain data values (h/Rh/wv/qp) are 4B/8B relaxed
// atomics loaded ONCE after a flag says they're ready; only flags and the
// ps mailboxes are polled.
// =====================================================================
typedef unsigned long long u64;
__device__ __forceinline__ float ald(const float* p) {
  return __hip_atomic_load(p, __ATOMIC_RELAXED, __HIP_MEMORY_SCOPE_AGENT);
}
__device__ __forceinline__ void ast(float* p, float v) {
  __hip_atomic_store(p, v, __ATOMIC_RELAXED, __HIP_MEMORY_SCOPE_AGENT);
}
__device__ __forceinline__ int ildi(const int* p) {
  return __hip_atomic_load(p, __ATOMIC_RELAXED, __HIP_MEMORY_SCOPE_AGENT);
}
__device__ __forceinline__ void iast(int* p, int v) {
  __hip_atomic_store(p, v, __ATOMIC_RELAXED, __HIP_MEMORY_SCOPE_AGENT);
}
__device__ __forceinline__ u64 ald64(const u64* p) {
  return __hip_atomic_load(p, __ATOMIC_RELAXED, __HIP_MEMORY_SCOPE_AGENT);
}
__device__ __forceinline__ void ast64(u64* p, u64 v) {
  __hip_atomic_store(p, v, __ATOMIC_RELAXED, __HIP_MEMORY_SCOPE_AGENT);
}
__device__ __forceinline__ u64 pk(float v, int j) {
  return ((u64)(unsigned)j << 32) | (u64)__float_as_uint(v);
}
__device__ __forceinline__ float lo(u64 u) { return __uint_as_float((unsigned)u); }
__device__ __forceinline__ float hi(u64 u) {
  return __uint_as_float((unsigned)(u >> 32));
}
__device__ __forceinline__ float pollv(const u64* p, int j) {
  u64 u = ald64(p);
  while ((unsigned)(u >> 32) != (unsigned)j) {
    __builtin_amdgcn_s_sleep(1);
    u = ald64(p);
  }
  return lo(u);
}

// Rotated tape addressing.
#define TIDX(n, e) ((n) * 64 + (((e) + (n)) & 63))

// 64 named weight scalars/thread. HARD LESSONS: local arrays -> scratch;
// VGPR budget = 65536/block_size, immovable; 64 floats fits 128 (R5/R7/R8).
#define REP32(M) M(0) M(1) M(2) M(3) M(4) M(5) M(6) M(7) M(8) M(9) M(10) \
  M(11) M(12) M(13) M(14) M(15) M(16) M(17) M(18) M(19) M(20) M(21) M(22) \
  M(23) M(24) M(25) M(26) M(27) M(28) M(29) M(30) M(31)

#define RW(i) const float wh##i = Whp[32 * (i)]; \
              const float ww##i = Wwp[32 * (i)];
#define MVI(i) { float4 hh = ht4[cseg + 32 * (i)]; \
  ah0 = fmaf(wh##i, hh.x, ah0); ah1 = fmaf(wh##i, hh.y, ah1); \
  ah2 = fmaf(wh##i, hh.z, ah2); ah3 = fmaf(wh##i, hh.w, ah3); \
  aw0 = fmaf(ww##i, hh.x, aw0); aw1 = fmaf(ww##i, hh.y, aw1); \
  aw2 = fmaf(ww##i, hh.z, aw2); aw3 = fmaf(ww##i, hh.w, aw3); }

// =====================================================================
// Group-shared persistent scan: 256 wgs x 512 threads (1 wg/CU, 8 waves).
// 4 groups of 64 wgs; group g serves batches 4g..4g+3; wg = (b_loc, es)
// owns (bsel, e-slice es) and produces rows R0..R0+16 of BOTH mats for
// all 4 batches (64 weight floats/thread in named regs).
// Sync: per-wg epoch flags fA (h ready) / fB (Rh/wv/qp ready), polled
// 64-lanes-wide (1 load/retry); data loaded ONCE after detect. ps stays
// a (value|tag) mailbox (scattered publishers).
// OVERWRITE SAFETY (untagged data): a wg reaches any step-j+1 publish
// only after its S2 fB(j) poll; fB(j) requires every group wg past B2,
// hence past its S0/S2 reads of the j-step values. Transitive ordering
// replaces tags. ps keeps ==j tags; producer reaches S5(j) only after
// fB(j) => all S0(j) ps reads done.
// Step (5 barriers):
//  (w0 prefetch wx/gate) | all waves poll fA>=j
//  S0 stage h (4x u64 -> 2x ds_write_b128, batch-transposed), ps pollv
//  B1 | S1 ws-reduce; matvec; publish Rh/wv (cseg0) + qp (lane0/wave)
//  B2 | tid0: fB=j
//  S2 w0:wa | w1:wa+pollfB+qp+attn -> c[n]=attn(1-wa), s2=sum attn*wa
//     | w2:pollfB+wv | w3:pollfB+Rh
//  B3 | S3 gather from OLD tape: read[e]=sum c[n]*tape_old + s2*wv[e]
//  B4 | S4 w0: h(j+1)=tanh(Rh+wx+read+b), publish h + fA=j+1, wx out;
//          all: tape lerp                     (last: sync, break)
//  B5 | S5 ps partials vs new tape -> mailbox tag j+1; loop
// =====================================================================
__global__ __launch_bounds__(512) void scan_kernel(
    const float* __restrict__ W_h, const float* __restrict__ W_wr,
    const float* __restrict__ b_h, const float* __restrict__ gate,
    float* __restrict__ wx,       // [B][T][D]; rows overwritten with h*gate
    float* __restrict__ hbuf,     // [B][1024] plain h values
    u64* __restrict__ psb,        // [B][16][64] score-partial mailboxes
    float* __restrict__ Rhb,      // [B][1024]
    float* __restrict__ wvb,      // [B][1024]
    float* __restrict__ qpb,      // [B][512] per-wave q partials
    int* __restrict__ flags,      // fA[256], fB[256]
    float* __restrict__ hfin,     // [B][1024] final h_work
    float* __restrict__ tape_out) // [B][64][1024]
{
  const int tid  = threadIdx.x;
  const int wg   = blockIdx.x;
  const int g    = wg >> 6;
  const int idx  = wg & 63;
  const int b_loc = idx >> 4;
  const int es   = idx & 15;
  const int gb   = g * 4;
  const int bsel = gb + b_loc;
  const int E0   = es * 64;
  const int R0   = es * 64 + b_loc * 16;
  const int w    = tid >> 6;
  const int lane = tid & 63;
  const int row  = tid >> 5;      // 0..15
  const int cseg = tid & 31;      // 32 col segments
  const int gr   = R0 + row;      // produced row (both mats)
  const int nwr  = tid >> 3;      // tape slot n
  const int ksb  = tid & 7;       // 8-elem e-block

  __shared__ float h_t[4096];       // batch-transposed h: h_t[4d+b], 16 KB
  __shared__ float tape_l[4096];    // rotated, 16 KB
  __shared__ float ws_lds[64], wa_lds[64], attn_lds[64];  // attn_lds = c[n]
  __shared__ float wv_lds[64], Rh_lds[64], h_own[64], read_lds[64];
  __shared__ float s2_lds;
  // Pad past 80 KB: exactly 1 wg/CU.
  __shared__ volatile float lds_pad[12288];
  lds_pad[tid] = 0.0f; lds_pad[tid + 512] = 0.0f;

  int* fA = flags;
  int* fB = flags + 256;

  // ---- weight preload: row gr of W_h AND W_wr, cols cseg+32i ----
  const float* Whp = W_h + (size_t)gr * 1024 + cseg;
  const float* Wwp = W_wr + (size_t)gr * 1024 + cseg;
  REP32(RW)

  const float4* ht4 = (const float4*)h_t;

  for (int i = tid; i < 4096; i += 512) tape_l[i] = 0.0f;

  float bh_r = 0.0f;
  if (w == 0) bh_r = b_h[E0 + lane];
  __syncthreads();

  // ---- prologue: h(1) = tanh(wx0 + b_h); ps tag 1 (= 0) ----
  if (w == 0) {
    size_t xi = (size_t)bsel * 1048576 + E0 + lane;
    float hv = tanhf(wx[xi] + bh_r);
    h_own[lane] = hv;
    ast(&hbuf[(size_t)bsel * 1024 + E0 + lane], hv);
    wx[xi] = hv * gate[xi];                 // output row 0
  }
  if (tid < 64) ast64(&psb[(size_t)bsel * 1024 + es * 64 + tid], pk(0.0f, 1));
  __syncthreads();                          // drains all publishes
  if (tid == 0) iast(&fA[wg], 1);

  for (int j = 1; j <= 1024; ++j) {
    const bool last = (j == 1024);

    // ---- w0: wx/gate prefetch (no deps) ----
    float wxv = 0.0f, gv = 0.0f;
    size_t xj = 0;
    if (w == 0 && !last) {
      xj  = (size_t)bsel * 1048576 + (size_t)j * 1024 + E0 + lane;
      wxv = wx[xj];
      gv  = gate[xj];
    }
    // ---- every wave polls fA >= j (1 flag load/lane/retry) ----
    {
      const int* f = &fA[g * 64];
      for (;;) {
        int v = ildi(&f[lane]);
        if (__all(v >= j)) break;
        __builtin_amdgcn_s_sleep(1);
      }
    }

    // ---- S0: stage h (plain u64 loads, ONE shot) + ps mailbox polls ----
    {
      u64 v0 = ald64((const u64*)hbuf + (size_t)(gb + 0) * 512 + tid);
      u64 v1 = ald64((const u64*)hbuf + (size_t)(gb + 1) * 512 + tid);
      u64 v2 = ald64((const u64*)hbuf + (size_t)(gb + 2) * 512 + tid);
      u64 v3 = ald64((const u64*)hbuf + (size_t)(gb + 3) * 512 + tid);
      ((float4*)h_t)[2 * tid]     = make_float4(lo(v0), lo(v1), lo(v2), lo(v3));
      ((float4*)h_t)[2 * tid + 1] = make_float4(hi(v0), hi(v1), hi(v2), hi(v3));
    }
    float p0 = pollv(&psb[(size_t)bsel * 1024 + (ksb * 2) * 64 + nwr], j);
    float p1 = pollv(&psb[(size_t)bsel * 1024 + (ksb * 2 + 1) * 64 + nwr], j);
    __syncthreads();   // B1

    // ---- S1: ws reduce; matvec; publish Rh/wv + per-wave qp ----
    {
      float s = p0 + p1;
      s += __shfl_xor(s, 1);
      s += __shfl_xor(s, 2);
      s += __shfl_xor(s, 4);
      if (ksb == 0) ws_lds[nwr] = s;
    }
    float ah0 = 0.0f, ah1 = 0.0f, ah2 = 0.0f, ah3 = 0.0f;
    float aw0 = 0.0f, aw1 = 0.0f, aw2 = 0.0f, aw3 = 0.0f;
    REP32(MVI)
#pragma unroll
    for (int m = 1; m < 32; m <<= 1) {
      ah0 += __shfl_xor(ah0, m); ah1 += __shfl_xor(ah1, m);
      ah2 += __shfl_xor(ah2, m); ah3 += __shfl_xor(ah3, m);
      aw0 += __shfl_xor(aw0, m); aw1 += __shfl_xor(aw1, m);
      aw2 += __shfl_xor(aw2, m); aw3 += __shfl_xor(aw3, m);
    }
    {  // per-wave qp partial: rows 2w,2w+1 combined via shfl 32
      float4 hrow = ht4[gr];
      float t0 = aw0 * hrow.x, t1 = aw1 * hrow.y;
      float t2 = aw2 * hrow.z, t3 = aw3 * hrow.w;
      t0 += __shfl_xor(t0, 32); t1 += __shfl_xor(t1, 32);
      t2 += __shfl_xor(t2, 32); t3 += __shfl_xor(t3, 32);
      if (lane == 0) {
        ast(&qpb[(size_t)(gb + 0) * 512 + idx * 8 + w], t0);
        ast(&qpb[(size_t)(gb + 1) * 512 + idx * 8 + w], t1);
        ast(&qpb[(size_t)(gb + 2) * 512 + idx * 8 + w], t2);
        ast(&qpb[(size_t)(gb + 3) * 512 + idx * 8 + w], t3);
      }
    }
    if (cseg == 0) {
      ast(&Rhb[(size_t)(gb + 0) * 1024 + gr], ah0);
      ast(&Rhb[(size_t)(gb + 1) * 1024 + gr], ah1);
      ast(&Rhb[(size_t)(gb + 2) * 1024 + gr], ah2);
      ast(&Rhb[(size_t)(gb + 3) * 1024 + gr], ah3);
      ast(&wvb[(size_t)(gb + 0) * 1024 + gr], aw0);
      ast(&wvb[(size_t)(gb + 1) * 1024 + gr], aw1);
      ast(&wvb[(size_t)(gb + 2) * 1024 + gr], aw2);
      ast(&wvb[(size_t)(gb + 3) * 1024 + gr], aw3);
    }
    __syncthreads();   // B2 (drains every wave's stores)
    if (tid == 0) iast(&fB[wg], j);

    // ---- S2: w0 wa | w1 q+attn->c,s2 | w2 wv | w3 Rh ----
    if (w == 0) {
      float s = ws_lds[lane] * SCALE_F;
      float m = s;
#pragma unroll
      for (int off = 1; off < 64; off <<= 1) m = fmaxf(m, __shfl_xor(m, off));
      float ex = __expf(s - m);
      float sum = ex;
#pragma unroll
      for (int off = 1; off < 64; off <<= 1) sum += __shfl_xor(sum, off);
      wa_lds[lane] = ex / sum;
    } else if (w == 1) {
      if (!last) {
        // redundant own wa (keeps the chain wave-local)
        float wsr = ws_lds[lane];
        float sm = wsr * SCALE_F;
        float m = sm;
#pragma unroll
        for (int off = 1; off < 64; off <<= 1) m = fmaxf(m, __shfl_xor(m, off));
        float ex = __expf(sm - m);
        float sum = ex;
#pragma unroll
        for (int off = 1; off < 64; off <<= 1) sum += __shfl_xor(sum, off);
        float wa_l = ex / sum;
        // poll fB, then ONE-shot qp loads
        const int* f = &fB[g * 64];
        for (;;) {
          int v = ildi(&f[lane]);
          if (__all(v >= j)) break;
          __builtin_amdgcn_s_sleep(1);
        }
        const float* qb = &qpb[(size_t)bsel * 512 + lane * 8];
        float qv = ald(qb + 0) + ald(qb + 1) + ald(qb + 2) + ald(qb + 3) +
                   ald(qb + 4) + ald(qb + 5) + ald(qb + 6) + ald(qb + 7);
#pragma unroll
        for (int off = 1; off < 64; off <<= 1) qv += __shfl_xor(qv, off);
        float rs = fmaf(wa_l, qv - wsr, wsr) * SCALE_F;
        float m2 = rs;
#pragma unroll
        for (int off = 1; off < 64; off <<= 1) m2 = fmaxf(m2, __shfl_xor(m2, off));
        float ex2 = __expf(rs - m2);
        float sum2 = ex2;
#pragma unroll
        for (int off = 1; off < 64; off <<= 1) sum2 += __shfl_xor(sum2, off);
        float att = ex2 / sum2;
        attn_lds[lane] = att * (1.0f - wa_l);       // c[n]
        float s2 = att * wa_l;
#pragma unroll
        for (int off = 1; off < 64; off <<= 1) s2 += __shfl_xor(s2, off);
        if (lane == 0) s2_lds = s2;
      }
    } else if (w == 2) {
      const int* f = &fB[g * 64];
      for (;;) {
        int v = ildi(&f[lane]);
        if (__all(v >= j)) break;
        __builtin_amdgcn_s_sleep(1);
      }
      wv_lds[lane] = ald(&wvb[(size_t)bsel * 1024 + E0 + lane]);
    } else if (w == 3) {
      const int* f = &fB[g * 64];
      for (;;) {
        int v = ildi(&f[lane]);
        if (__all(v >= j)) break;
        __builtin_amdgcn_s_sleep(1);
      }
      Rh_lds[lane] = ald(&Rhb[(size_t)bsel * 1024 + E0 + lane]);
    }
    __syncthreads();   // B3

    // ---- S3: gather from OLD tape (identity; pre-lerp, race-free) ----
    if (!last) {
      int ge = tid >> 3, gn = tid & 7;
      float gsum = 0.0f;
#pragma unroll
      for (int i = 0; i < 8; ++i) {
        int n = gn * 8 + i;
        gsum = fmaf(attn_lds[n], tape_l[TIDX(n, ge)], gsum);
      }
      gsum += __shfl_xor(gsum, 1);
      gsum += __shfl_xor(gsum, 2);
      gsum += __shfl_xor(gsum, 4);
      if (gn == 0) read_lds[ge] = gsum + s2_lds * wv_lds[ge];
    }
    __syncthreads();   // B4

    // ---- S4: w0 h(j+1)+publish+fA | all: tape lerp ----
    if (w == 0 && !last) {
      float hv = tanhf(Rh_lds[lane] + wxv + read_lds[lane] + bh_r);
      h_own[lane] = hv;
      ast(&hbuf[(size_t)bsel * 1024 + E0 + lane], hv);
      wx[xj] = hv * gv;
      asm volatile("s_waitcnt vmcnt(0)" ::: "memory");
      if (lane == 0) iast(&fA[wg], j + 1);
    }
    {
      float wa = wa_lds[nwr];
#pragma unroll
      for (int i = 0; i < 8; ++i) {
        int e = ksb * 8 + i;
        int ix = TIDX(nwr, e);
        float t = tape_l[ix];
        tape_l[ix] = fmaf(wa, wv_lds[e] - t, t);
      }
    }
    if (last) { __syncthreads(); break; }
    __syncthreads();   // B5

    // ---- S5: ps partials vs NEW tape -> mailbox tag j+1 ----
    {
      float s = 0.0f;
#pragma unroll
      for (int i = 0; i < 8; ++i) {
        int e = ksb * 8 + i;
        s = fmaf(h_own[e], tape_l[TIDX(nwr, e)], s);
      }
      s += __shfl_xor(s, 1);
      s += __shfl_xor(s, 2);
      s += __shfl_xor(s, 4);
      if (ksb == 0)
        ast64(&psb[(size_t)bsel * 1024 + es * 64 + nwr], pk(s, j + 1));
    }
    // no barrier: next-iteration h_t writes are gated by B1 before use;
    // tape_l next written only after B4 of next step.
  }

  // ---- epilogue: final tape slice + final h_work ----
#pragma unroll
  for (int i = 0; i < 8; ++i) {
    int e = ksb * 8 + i;
    tape_out[(size_t)(bsel * 64 + nwr) * 1024 + E0 + e] = tape_l[TIDX(nwr, e)];
  }
  if (w == 0) hfin[(size_t)bsel * 1024 + E0 + lane] = h_own[lane];
}

// =====================================================================
extern "C" void kernel_launch(void* const* d_in, const int* in_sizes, int n_in,
                              void* d_out, int out_size, void* d_ws, size_t ws_size,
                              hipStream_t stream) {
  (void)in_sizes; (void)n_in; (void)out_size; (void)ws_size;
  const float* x      = (const float*)d_in[0];
  const float* in_w   = (const float*)d_in[1];
  const float* out_w  = (const float*)d_in[2];
  const float* gate_w = (const float*)d_in[3];
  const float* W_x    = (const float*)d_in[4];
  const float* W_h    = (const float*)d_in[5];
  const float* W_wr   = (const float*)d_in[6];
  const float* b_h    = (const float*)d_in[7];

  float* out  = (float*)d_out;                     // [16][1024][1024]
  float* tape = out + (size_t)16 * 1024 * 1024;    // [16][64][1024]
  float* hfin = tape + (size_t)16 * 64 * 1024;     // [16][1024]

  float* ws = (float*)d_ws;
  // scan-time buffers overlay M1's region (M1 dead before scan)
  float* hbuf = ws;                      // 16384 floats
  u64*   psb  = (u64*)(ws + 16384);      // 16K mailboxes (32768 floats)
  float* Rhb  = ws + 49152;              // 16384
  float* wvb  = ws + 65536;              // 16384
  float* qpb  = ws + 81920;              // 8192
  int*   flg  = (int*)(ws + 90112);      // fA[256], fB[256]
  float* M1   = ws;                      // [1024][1024]
  float* wx   = ws + (1 << 20);          // [16][1024][1024]

  float* gate = out;                     // park gate in d_out region

  dim3 blk(256);
  gemm_nt<false, 0><<<dim3(16, 16), blk, 0, stream>>>(W_x, in_w, M1, 1024, 1024, 1024);
  gemm_nt<true, 1><<<dim3(16, 256), blk, 0, stream>>>(x, gate_w, gate, 16384, 1024, 1024);
  gemm_nt<true, 0><<<dim3(16, 256), blk, 0, stream>>>(x, M1, wx, 16384, 1024, 1024);
  hipMemsetAsync(ws, 0, 90624 * sizeof(float), stream);  // zero tags + flags
  scan_kernel<<<256, 512, 0, stream>>>(W_h, W_wr, b_h, gate, wx, hbuf, psb,
                                       Rhb, wvb, qpb, flg, hfin, tape);
  gemm_nt<true, 0><<<dim3(16, 256), blk, 0, stream>>>(wx, out_w, out, 16384, 1024, 1024);
}